// Round 1
// baseline (577.266 us; speedup 1.0000x reference)
//
#include <hip/hip_runtime.h>
#include <stdint.h>

#define DEV __device__ __forceinline__

typedef __attribute__((ext_vector_type(8))) short short8;
typedef __attribute__((ext_vector_type(4))) float floatx4;

// problem dims
#define BATCH 128
#define TT    197
#define DD    768
#define NH    12
#define NROWS (BATCH*TT)   // 25216 = 197*128
#define G4H   3072         // 4*H rows of gate weights

DEV uint16_t f2bf(float f) {
    union { float f; uint32_t u; } v; v.f = f;
    uint32_t r = (v.u + 0x7FFF + ((v.u >> 16) & 1)) >> 16;  // RNE
    return (uint16_t)r;
}

DEV floatx4 mfma16(short8 a, short8 b, floatx4 c) {
    return __builtin_amdgcn_mfma_f32_16x16x32_bf16(a, b, c, 0, 0, 0);
}

DEV float sigf(float x)   { return __builtin_amdgcn_rcpf(1.0f + __expf(-x)); }
DEV float tanhf_(float x) { return 1.0f - 2.0f * __builtin_amdgcn_rcpf(1.0f + __expf(2.0f * x)); }

// ---------------- fp32 -> bf16 conversion ----------------
__global__ void cvt_bf16(const float* __restrict__ src, uint16_t* __restrict__ dst, int n4) {
    int i = blockIdx.x * blockDim.x + threadIdx.x;
    int stride = gridDim.x * blockDim.x;
    for (; i < n4; i += stride) {
        float4 v = ((const float4*)src)[i];
        ushort4 o;
        o.x = f2bf(v.x); o.y = f2bf(v.y); o.z = f2bf(v.z); o.w = f2bf(v.w);
        ((ushort4*)dst)[i] = o;
    }
}

// ---------------- bf16 MFMA GEMM: C[M,N] = A[M,K] @ Bw[N,K]^T + bias ----------------
// block tile 128(M) x 64(N), K-step 32. 4 waves: wave w owns m-tiles {2w,2w+1}, all 4 n-tiles.
// LDS chunks laid out in frag-identity order: staging store addr == frag read addr (conflict-free).
template<int STORE_BF16, int REMAP>
__global__ __launch_bounds__(256) void gemm_bf16(
    const uint16_t* __restrict__ A,    // [M][K] bf16
    const uint16_t* __restrict__ Bw,   // [N][K] bf16 (weight; we apply its transpose)
    const float*    __restrict__ bias, // [N] fp32
    void*           __restrict__ C,
    int K, int Ntot)
{
    __shared__ __attribute__((aligned(16))) uint16_t Atile[8 * 512];
    __shared__ __attribute__((aligned(16))) uint16_t Btile[4 * 512];

    const int tid  = threadIdx.x;
    const int wv   = tid >> 6;
    const int lane = tid & 63;
    const int ln   = lane & 15;
    const int kq   = lane >> 4;
    const int m0   = blockIdx.y * 128;
    const int n0   = blockIdx.x * 64;

    floatx4 acc[2][4];
#pragma unroll
    for (int a = 0; a < 2; a++)
#pragma unroll
        for (int b = 0; b < 4; b++) acc[a][b] = (floatx4){0.f, 0.f, 0.f, 0.f};

    const uint16_t* Arow0 = A  + (size_t)(m0 + (2*wv+0)*16 + ln) * K + kq*8;
    const uint16_t* Arow1 = A  + (size_t)(m0 + (2*wv+1)*16 + ln) * K + kq*8;
    const uint16_t* Brow  = Bw + (size_t)(n0 + wv*16      + ln) * K + kq*8;

    uint16_t* Adst0 = &Atile[(2*wv+0)*512 + lane*8];
    uint16_t* Adst1 = &Atile[(2*wv+1)*512 + lane*8];
    uint16_t* Bdst  = &Btile[ wv     *512 + lane*8];

    for (int k0 = 0; k0 < K; k0 += 32) {
        uint4 a0 = *(const uint4*)(Arow0 + k0);
        uint4 a1 = *(const uint4*)(Arow1 + k0);
        uint4 bb = *(const uint4*)(Brow  + k0);
        __syncthreads();                       // prior frag reads done before overwrite
        *(uint4*)Adst0 = a0;
        *(uint4*)Adst1 = a1;
        *(uint4*)Bdst  = bb;
        __syncthreads();                       // tiles ready
        short8 af0 = *(const short8*)&Atile[(2*wv+0)*512 + lane*8];
        short8 af1 = *(const short8*)&Atile[(2*wv+1)*512 + lane*8];
        short8 bf[4];
#pragma unroll
        for (int nt = 0; nt < 4; nt++) bf[nt] = *(const short8*)&Btile[nt*512 + lane*8];
#pragma unroll
        for (int nt = 0; nt < 4; nt++) {
            acc[0][nt] = mfma16(af0, bf[nt], acc[0][nt]);
            acc[1][nt] = mfma16(af1, bf[nt], acc[1][nt]);
        }
    }

#pragma unroll
    for (int mt = 0; mt < 2; mt++)
#pragma unroll
        for (int nt = 0; nt < 4; nt++) {
            int n = n0 + nt*16 + ln;
            float bv = bias[n];
#pragma unroll
            for (int r = 0; r < 4; r++) {
                int m = m0 + (2*wv+mt)*16 + kq*4 + r;
                float val = acc[mt][nt][r] + bv;
                int row;
                if (REMAP) { int b = m / 197; int t = m - b*197; row = t*128 + b; }
                else       { row = m; }
                if (STORE_BF16) ((uint16_t*)C)[(size_t)row * Ntot + n] = f2bf(val);
                else            ((float*)C)[(size_t)row * Ntot + n]    = val;
            }
        }
}

// ---------------- fused bidirectional multi-head LSTM ----------------
// grid (8 batch-chunks, 12 heads, 2 dirs), 256 threads = 4 waves.
// wave w owns units [16w,16w+16) of its head: 4 gate-type C-tiles [16 units x 16 batches].
// A-frags (w_ih + w_hh MFMA fragments) persistent in registers; c/h state fp32 in regs;
// h exchanged through padded LDS (stride 72 bf16); x-frags prefetched from global.
__global__ __launch_bounds__(256) void lstm_fused(
    const uint16_t* __restrict__ pre,   // [T][B][768] bf16
    const uint16_t* __restrict__ wih_f, const uint16_t* __restrict__ whh_f,
    const uint16_t* __restrict__ wih_r, const uint16_t* __restrict__ whh_r,
    const float* __restrict__ bih_f, const float* __restrict__ bhh_f,
    const float* __restrict__ bih_r, const float* __restrict__ bhh_r,
    uint16_t* __restrict__ hout)        // [B][T][1536] bf16
{
    __shared__ __attribute__((aligned(16))) uint16_t hbuf[16][72];

    const int tid  = threadIdx.x;
    const int wv   = tid >> 6;
    const int lane = tid & 63;
    const int ln   = lane & 15;
    const int q    = lane >> 4;
    const int b0   = blockIdx.x * 16;
    const int head = blockIdx.y;
    const int dir  = blockIdx.z;
    const int ub   = wv * 16;

    const uint16_t* wih = dir ? wih_r : wih_f;
    const uint16_t* whh = dir ? whh_r : whh_f;
    const float*    bih = dir ? bih_r : bih_f;
    const float*    bhh = dir ? bhh_r : bhh_f;

    // persistent A-fragments: [gate type][k-step]
    short8 aih[4][2], ahh[4][2];
#pragma unroll
    for (int t = 0; t < 4; t++) {
        size_t row = (size_t)(t*768 + head*64 + ub + ln);
#pragma unroll
        for (int s = 0; s < 2; s++) {
            aih[t][s] = *(const short8*)(wih + row*768 + head*64 + s*32 + q*8);
            ahh[t][s] = *(const short8*)(whh + row*768 + head*64 + s*32 + q*8);
        }
    }
    float biasv[4][4];
#pragma unroll
    for (int t = 0; t < 4; t++)
#pragma unroll
        for (int r = 0; r < 4; r++) {
            int row = t*768 + head*64 + ub + q*4 + r;
            biasv[t][r] = bih[row] + bhh[row];
        }

    for (int i = tid; i < 16*72; i += 256) ((uint16_t*)hbuf)[i] = 0;
    float c[4] = {0.f, 0.f, 0.f, 0.f};
    __syncthreads();

    const uint16_t* xbase = pre + head*64 + q*8;
    int t_cur = dir ? (TT - 1) : 0;
    const int tstep = dir ? -1 : 1;
    size_t xo = (size_t)(t_cur*128 + b0 + ln) * 768;
    short8 xv0 = *(const short8*)(xbase + xo);
    short8 xv1 = *(const short8*)(xbase + xo + 32);

    for (int step = 0; step < TT; step++) {
        short8 cx0 = xv0, cx1 = xv1;
        int t_next = t_cur + tstep;
        if (step + 1 < TT) {   // prefetch next timestep's x fragments
            size_t xo2 = (size_t)(t_next*128 + b0 + ln) * 768;
            xv0 = *(const short8*)(xbase + xo2);
            xv1 = *(const short8*)(xbase + xo2 + 32);
        }
        short8 hb0 = *(const short8*)&hbuf[ln][0*32 + q*8];
        short8 hb1 = *(const short8*)&hbuf[ln][1*32 + q*8];

        floatx4 acc[4];
#pragma unroll
        for (int t = 0; t < 4; t++)
            acc[t] = (floatx4){biasv[t][0], biasv[t][1], biasv[t][2], biasv[t][3]};
#pragma unroll
        for (int t = 0; t < 4; t++) {
            acc[t] = mfma16(aih[t][0], cx0, acc[t]);
            acc[t] = mfma16(ahh[t][0], hb0, acc[t]);
            acc[t] = mfma16(aih[t][1], cx1, acc[t]);
            acc[t] = mfma16(ahh[t][1], hb1, acc[t]);
        }

        union { uint16_t s[4]; uint2 v; } hp;
#pragma unroll
        for (int r = 0; r < 4; r++) {
            float ig = sigf(acc[0][r]);
            float fg = sigf(acc[1][r]);
            float gg = tanhf_(acc[2][r]);
            float og = sigf(acc[3][r]);
            c[r] = fg * c[r] + ig * gg;
            float hv = og * tanhf_(c[r]);
            hp.s[r] = f2bf(hv);
        }

        __syncthreads();   // A: all waves done reading h_{t-1}
        *(uint2*)&hbuf[ln][ub + q*4] = hp.v;
        __syncthreads();   // B: new h visible

        {   // coalesced h -> global (read back from LDS)
            int bl = tid >> 4;
            int dw = tid & 15;
            uint2 v = *(const uint2*)&hbuf[bl][dw*4];
            size_t off = ((size_t)(b0 + bl)*TT + t_cur) * 1536 + dir*768 + head*64 + dw*4;
            *(uint2*)(hout + off) = v;
        }
        t_cur = t_next;
    }
}

extern "C" void kernel_launch(void* const* d_in, const int* in_sizes, int n_in,
                              void* d_out, int out_size, void* d_ws, size_t ws_size,
                              hipStream_t stream) {
    (void)in_sizes; (void)n_in; (void)out_size; (void)ws_size;
    const float* x     = (const float*)d_in[0];
    const float* pre_w = (const float*)d_in[1];
    const float* pre_b = (const float*)d_in[2];
    const float* wihf  = (const float*)d_in[3];
    const float* whhf  = (const float*)d_in[4];
    const float* bihf  = (const float*)d_in[5];
    const float* bhhf  = (const float*)d_in[6];
    const float* wihr  = (const float*)d_in[7];
    const float* whhr  = (const float*)d_in[8];
    const float* bihr  = (const float*)d_in[9];
    const float* bhhr  = (const float*)d_in[10];
    const float* projw = (const float*)d_in[11];
    const float* projb = (const float*)d_in[12];
    float* out = (float*)d_out;

    // workspace layout (bf16 elements), ~177 MB total
    uint16_t* W = (uint16_t*)d_ws;
    uint16_t* xb     = W; W += (size_t)NROWS * DD;     // x in bf16           [B*T][768]
    uint16_t* bwpre  = W; W += (size_t)DD * DD;        // pre_w bf16          [768][768]
    uint16_t* bwihf  = W; W += (size_t)G4H * DD;
    uint16_t* bwhhf  = W; W += (size_t)G4H * DD;
    uint16_t* bwihr  = W; W += (size_t)G4H * DD;
    uint16_t* bwhhr  = W; W += (size_t)G4H * DD;
    uint16_t* bwproj = W; W += (size_t)DD * 2 * DD;    // proj_w bf16         [768][1536]
    uint16_t* preb   = W; W += (size_t)NROWS * DD;     // pre-proj, [T][B][768] bf16
    uint16_t* houtb  = W; W += (size_t)NROWS * 2 * DD; // lstm out  [B][T][1536] bf16

    auto cvt = [&](const float* s, uint16_t* d, size_t n) {
        int n4 = (int)(n / 4);
        int blocks = (n4 + 255) / 256; if (blocks > 4096) blocks = 4096;
        hipLaunchKernelGGL(cvt_bf16, dim3(blocks), dim3(256), 0, stream, s, d, n4);
    };
    cvt(x,     xb,     (size_t)NROWS * DD);
    cvt(pre_w, bwpre,  (size_t)DD * DD);
    cvt(wihf,  bwihf,  (size_t)G4H * DD);
    cvt(whhf,  bwhhf,  (size_t)G4H * DD);
    cvt(wihr,  bwihr,  (size_t)G4H * DD);
    cvt(whhr,  bwhhr,  (size_t)G4H * DD);
    cvt(projw, bwproj, (size_t)DD * 2 * DD);

    // S1: pre = x @ pre_w.T + pre_b, stored bf16 transposed to [T][B][768]
    hipLaunchKernelGGL((gemm_bf16<1, 1>), dim3(12, 197), dim3(256), 0, stream,
                       xb, bwpre, pre_b, (void*)preb, DD, DD);
    // S2+S3 fused: bidirectional block-diagonal LSTM
    hipLaunchKernelGGL(lstm_fused, dim3(8, 12, 2), dim3(256), 0, stream,
                       preb, bwihf, bwhhf, bwihr, bwhhr,
                       bihf, bhhf, bihr, bhhr, houtb);
    // S4: out = [hf|hr] @ proj_w.T + proj_b (fp32 out)
    hipLaunchKernelGGL((gemm_bf16<0, 0>), dim3(12, 197), dim3(256), 0, stream,
                       houtb, bwproj, projb, (void*)out, 2 * DD, DD);
}

// Round 2
// 511.800 us; speedup vs baseline: 1.1279x; 1.1279x over previous
//
#include <hip/hip_runtime.h>
#include <stdint.h>

#define DEV __device__ __forceinline__

typedef __attribute__((ext_vector_type(8))) short short8;
typedef __attribute__((ext_vector_type(4))) float floatx4;

// problem dims
#define BATCH 128
#define TT    197
#define DD    768
#define NH    12
#define NROWS (BATCH*TT)   // 25216 = 197*128
#define G4H   3072         // 4*H rows of gate weights

DEV uint16_t f2bf(float f) {
    union { float f; uint32_t u; } v; v.f = f;
    uint32_t r = (v.u + 0x7FFF + ((v.u >> 16) & 1)) >> 16;  // RNE
    return (uint16_t)r;
}

DEV floatx4 mfma16(short8 a, short8 b, floatx4 c) {
    return __builtin_amdgcn_mfma_f32_16x16x32_bf16(a, b, c, 0, 0, 0);
}

DEV float sigf(float x)   { return __builtin_amdgcn_rcpf(1.0f + __expf(-x)); }
DEV float tanhf_(float x) { return 1.0f - 2.0f * __builtin_amdgcn_rcpf(1.0f + __expf(2.0f * x)); }

// async global->LDS, 16B per lane; lds base must be wave-uniform (HW adds lane*16)
DEV void async16(const uint16_t* g, uint16_t* l) {
    __builtin_amdgcn_global_load_lds(
        (const __attribute__((address_space(1))) unsigned int*)g,
        (__attribute__((address_space(3))) unsigned int*)l,
        16, 0, 0);
}

// ---------------- fp32 -> bf16 conversion ----------------
__global__ void cvt_bf16(const float* __restrict__ src, uint16_t* __restrict__ dst, int n4) {
    int i = blockIdx.x * blockDim.x + threadIdx.x;
    int stride = gridDim.x * blockDim.x;
    for (; i < n4; i += stride) {
        float4 v = ((const float4*)src)[i];
        ushort4 o;
        o.x = f2bf(v.x); o.y = f2bf(v.y); o.z = f2bf(v.z); o.w = f2bf(v.w);
        ((ushort4*)dst)[i] = o;
    }
}

// ---------------- bf16 MFMA GEMM (m97-style): C[M,N] = A[M,K] @ Bw[N,K]^T + bias ----
// 128x128 block tile, 256 threads = 4 waves, each wave owns a 64x64 quadrant
// (4x4 grid of 16x16 MFMA tiles). K-step 32.
// LDS: 16 chunks of 16(rows)x32(k) bf16, identity layout: element for compute-lane
// l of chunk c lives at chunk_base + l*16B, so global_load_lds (wave-uniform base +
// lane*16) stages directly into frag-read order, and ds_read_b128 is conflict-free.
template<int STORE_BF16, int REMAP>
__global__ __launch_bounds__(256) void gemm128(
    const uint16_t* __restrict__ A,    // [M][K] bf16
    const uint16_t* __restrict__ Bw,   // [N][K] bf16 (weight; we apply its transpose)
    const float*    __restrict__ bias, // [N] fp32
    void*           __restrict__ C,
    int K, int Ntot)
{
    __shared__ __attribute__((aligned(16))) uint16_t As[128 * 32];  // 8 chunks x 512 elem
    __shared__ __attribute__((aligned(16))) uint16_t Bs[128 * 32];

    const int tid  = threadIdx.x;
    const int wv   = tid >> 6;
    const int lane = tid & 63;
    const int ln   = lane & 15;
    const int q    = lane >> 4;
    const int m0   = blockIdx.y * 128;
    const int n0   = blockIdx.x * 128;
    const int wm   = wv >> 1;   // wave's quadrant row (0..1)
    const int wn   = wv & 1;    // wave's quadrant col (0..1)

    floatx4 acc[4][4];
#pragma unroll
    for (int a = 0; a < 4; a++)
#pragma unroll
        for (int b = 0; b < 4; b++) acc[a][b] = (floatx4){0.f, 0.f, 0.f, 0.f};

    // staging: wave wv loads A chunks {2wv, 2wv+1} and B chunks {2wv, 2wv+1}.
    // lane l fetches the element block destined for chunk_base + l*16B:
    // row = chunk*16 + (l&15), k-offset = (l>>4)*8.
    const uint16_t* gA0 = A  + (size_t)(m0 + (2*wv+0)*16 + ln) * K + q*8;
    const uint16_t* gA1 = A  + (size_t)(m0 + (2*wv+1)*16 + ln) * K + q*8;
    const uint16_t* gB0 = Bw + (size_t)(n0 + (2*wv+0)*16 + ln) * K + q*8;
    const uint16_t* gB1 = Bw + (size_t)(n0 + (2*wv+1)*16 + ln) * K + q*8;
    uint16_t* lA0 = &As[(2*wv+0) * 512];   // wave-uniform LDS bases
    uint16_t* lA1 = &As[(2*wv+1) * 512];
    uint16_t* lB0 = &Bs[(2*wv+0) * 512];
    uint16_t* lB1 = &Bs[(2*wv+1) * 512];

    for (int k0 = 0; k0 < K; k0 += 32) {
        __syncthreads();                 // previous iteration's frag reads done
        async16(gA0 + k0, lA0);
        async16(gA1 + k0, lA1);
        async16(gB0 + k0, lB0);
        async16(gB1 + k0, lB1);
        __syncthreads();                 // vmcnt(0) drained by barrier semantics

        short8 af[4], bf[4];
#pragma unroll
        for (int mt = 0; mt < 4; mt++)
            af[mt] = *(const short8*)&As[(wm*4 + mt)*512 + lane*8];
#pragma unroll
        for (int nt = 0; nt < 4; nt++)
            bf[nt] = *(const short8*)&Bs[(wn*4 + nt)*512 + lane*8];
#pragma unroll
        for (int mt = 0; mt < 4; mt++)
#pragma unroll
            for (int nt = 0; nt < 4; nt++)
                acc[mt][nt] = mfma16(af[mt], bf[nt], acc[mt][nt]);
    }

    // epilogue: C/D layout col=lane&15 (maps to n), row=(lane>>4)*4+r (maps to m)
#pragma unroll
    for (int mt = 0; mt < 4; mt++)
#pragma unroll
        for (int nt = 0; nt < 4; nt++) {
            int n = n0 + (wn*4 + nt)*16 + ln;
            float bv = bias[n];
#pragma unroll
            for (int r = 0; r < 4; r++) {
                int m = m0 + (wm*4 + mt)*16 + q*4 + r;
                float val = acc[mt][nt][r] + bv;
                int row;
                if (REMAP) { int b = m / 197; int t = m - b*197; row = t*128 + b; }
                else       { row = m; }
                if (STORE_BF16) ((uint16_t*)C)[(size_t)row * Ntot + n] = f2bf(val);
                else            ((float*)C)[(size_t)row * Ntot + n]    = val;
            }
        }
}

// ---------------- fused bidirectional multi-head LSTM ----------------
// grid (8 batch-chunks, 12 heads, 2 dirs), 256 threads = 4 waves.
// wave w owns units [16w,16w+16) of its head: 4 gate-type C-tiles [16 units x 16 batches].
// A-frags (w_ih + w_hh MFMA fragments) persistent in registers; c/h state fp32 in regs;
// h exchanged through padded LDS (stride 72 bf16); x-frags prefetched from global.
__global__ __launch_bounds__(256) void lstm_fused(
    const uint16_t* __restrict__ pre,   // [T][B][768] bf16
    const uint16_t* __restrict__ wih_f, const uint16_t* __restrict__ whh_f,
    const uint16_t* __restrict__ wih_r, const uint16_t* __restrict__ whh_r,
    const float* __restrict__ bih_f, const float* __restrict__ bhh_f,
    const float* __restrict__ bih_r, const float* __restrict__ bhh_r,
    uint16_t* __restrict__ hout)        // [B][T][1536] bf16
{
    __shared__ __attribute__((aligned(16))) uint16_t hbuf[16][72];

    const int tid  = threadIdx.x;
    const int wv   = tid >> 6;
    const int lane = tid & 63;
    const int ln   = lane & 15;
    const int q    = lane >> 4;
    const int b0   = blockIdx.x * 16;
    const int head = blockIdx.y;
    const int dir  = blockIdx.z;
    const int ub   = wv * 16;

    const uint16_t* wih = dir ? wih_r : wih_f;
    const uint16_t* whh = dir ? whh_r : whh_f;
    const float*    bih = dir ? bih_r : bih_f;
    const float*    bhh = dir ? bhh_r : bhh_f;

    // persistent A-fragments: [gate type][k-step]
    short8 aih[4][2], ahh[4][2];
#pragma unroll
    for (int t = 0; t < 4; t++) {
        size_t row = (size_t)(t*768 + head*64 + ub + ln);
#pragma unroll
        for (int s = 0; s < 2; s++) {
            aih[t][s] = *(const short8*)(wih + row*768 + head*64 + s*32 + q*8);
            ahh[t][s] = *(const short8*)(whh + row*768 + head*64 + s*32 + q*8);
        }
    }
    float biasv[4][4];
#pragma unroll
    for (int t = 0; t < 4; t++)
#pragma unroll
        for (int r = 0; r < 4; r++) {
            int row = t*768 + head*64 + ub + q*4 + r;
            biasv[t][r] = bih[row] + bhh[row];
        }

    for (int i = tid; i < 16*72; i += 256) ((uint16_t*)hbuf)[i] = 0;
    float c[4] = {0.f, 0.f, 0.f, 0.f};
    __syncthreads();

    const uint16_t* xbase = pre + head*64 + q*8;
    int t_cur = dir ? (TT - 1) : 0;
    const int tstep = dir ? -1 : 1;
    size_t xo = (size_t)(t_cur*128 + b0 + ln) * 768;
    short8 xv0 = *(const short8*)(xbase + xo);
    short8 xv1 = *(const short8*)(xbase + xo + 32);

    for (int step = 0; step < TT; step++) {
        short8 cx0 = xv0, cx1 = xv1;
        int t_next = t_cur + tstep;
        if (step + 1 < TT) {   // prefetch next timestep's x fragments
            size_t xo2 = (size_t)(t_next*128 + b0 + ln) * 768;
            xv0 = *(const short8*)(xbase + xo2);
            xv1 = *(const short8*)(xbase + xo2 + 32);
        }
        short8 hb0 = *(const short8*)&hbuf[ln][0*32 + q*8];
        short8 hb1 = *(const short8*)&hbuf[ln][1*32 + q*8];

        floatx4 acc[4];
#pragma unroll
        for (int t = 0; t < 4; t++)
            acc[t] = (floatx4){biasv[t][0], biasv[t][1], biasv[t][2], biasv[t][3]};
#pragma unroll
        for (int t = 0; t < 4; t++) {
            acc[t] = mfma16(aih[t][0], cx0, acc[t]);
            acc[t] = mfma16(ahh[t][0], hb0, acc[t]);
            acc[t] = mfma16(aih[t][1], cx1, acc[t]);
            acc[t] = mfma16(ahh[t][1], hb1, acc[t]);
        }

        union { uint16_t s[4]; uint2 v; } hp;
#pragma unroll
        for (int r = 0; r < 4; r++) {
            float ig = sigf(acc[0][r]);
            float fg = sigf(acc[1][r]);
            float gg = tanhf_(acc[2][r]);
            float og = sigf(acc[3][r]);
            c[r] = fg * c[r] + ig * gg;
            float hv = og * tanhf_(c[r]);
            hp.s[r] = f2bf(hv);
        }

        __syncthreads();   // A: all waves done reading h_{t-1}
        *(uint2*)&hbuf[ln][ub + q*4] = hp.v;
        __syncthreads();   // B: new h visible

        {   // coalesced h -> global (read back from LDS)
            int bl = tid >> 4;
            int dw = tid & 15;
            uint2 v = *(const uint2*)&hbuf[bl][dw*4];
            size_t off = ((size_t)(b0 + bl)*TT + t_cur) * 1536 + dir*768 + head*64 + dw*4;
            *(uint2*)(hout + off) = v;
        }
        t_cur = t_next;
    }
}

extern "C" void kernel_launch(void* const* d_in, const int* in_sizes, int n_in,
                              void* d_out, int out_size, void* d_ws, size_t ws_size,
                              hipStream_t stream) {
    (void)in_sizes; (void)n_in; (void)out_size; (void)ws_size;
    const float* x     = (const float*)d_in[0];
    const float* pre_w = (const float*)d_in[1];
    const float* pre_b = (const float*)d_in[2];
    const float* wihf  = (const float*)d_in[3];
    const float* whhf  = (const float*)d_in[4];
    const float* bihf  = (const float*)d_in[5];
    const float* bhhf  = (const float*)d_in[6];
    const float* wihr  = (const float*)d_in[7];
    const float* whhr  = (const float*)d_in[8];
    const float* bihr  = (const float*)d_in[9];
    const float* bhhr  = (const float*)d_in[10];
    const float* projw = (const float*)d_in[11];
    const float* projb = (const float*)d_in[12];
    float* out = (float*)d_out;

    // workspace layout (bf16 elements), ~177 MB total
    uint16_t* W = (uint16_t*)d_ws;
    uint16_t* xb     = W; W += (size_t)NROWS * DD;     // x in bf16           [B*T][768]
    uint16_t* bwpre  = W; W += (size_t)DD * DD;        // pre_w bf16          [768][768]
    uint16_t* bwihf  = W; W += (size_t)G4H * DD;
    uint16_t* bwhhf  = W; W += (size_t)G4H * DD;
    uint16_t* bwihr  = W; W += (size_t)G4H * DD;
    uint16_t* bwhhr  = W; W += (size_t)G4H * DD;
    uint16_t* bwproj = W; W += (size_t)DD * 2 * DD;    // proj_w bf16         [768][1536]
    uint16_t* preb   = W; W += (size_t)NROWS * DD;     // pre-proj, [T][B][768] bf16
    uint16_t* houtb  = W; W += (size_t)NROWS * 2 * DD; // lstm out  [B][T][1536] bf16

    auto cvt = [&](const float* s, uint16_t* d, size_t n) {
        int n4 = (int)(n / 4);
        int blocks = (n4 + 255) / 256; if (blocks > 4096) blocks = 4096;
        hipLaunchKernelGGL(cvt_bf16, dim3(blocks), dim3(256), 0, stream, s, d, n4);
    };
    cvt(x,     xb,     (size_t)NROWS * DD);
    cvt(pre_w, bwpre,  (size_t)DD * DD);
    cvt(wihf,  bwihf,  (size_t)G4H * DD);
    cvt(whhf,  bwhhf,  (size_t)G4H * DD);
    cvt(wihr,  bwihr,  (size_t)G4H * DD);
    cvt(whhr,  bwhhr,  (size_t)G4H * DD);
    cvt(projw, bwproj, (size_t)DD * 2 * DD);

    // S1: pre = x @ pre_w.T + pre_b, stored bf16 transposed to [T][B][768]
    hipLaunchKernelGGL((gemm128<1, 1>), dim3(6, 197), dim3(256), 0, stream,
                       xb, bwpre, pre_b, (void*)preb, DD, DD);
    // S2+S3 fused: bidirectional block-diagonal LSTM
    hipLaunchKernelGGL(lstm_fused, dim3(8, 12, 2), dim3(256), 0, stream,
                       preb, bwihf, bwhhf, bwihr, bwhhr,
                       bihf, bhhf, bihr, bhhr, houtb);
    // S4: out = [hf|hr] @ proj_w.T + proj_b (fp32 out)
    hipLaunchKernelGGL((gemm128<0, 0>), dim3(6, 197), dim3(256), 0, stream,
                       houtb, bwproj, projb, (void*)out, 2 * DD, DD);
}